// Round 2
// baseline (100.361 us; speedup 1.0000x reference)
//
#include <hip/hip_runtime.h>
#include <math.h>

#define EPS   1e-6f
#define BB    256
#define NNEG  1000
#define HH    3
#define DD    128
#define NCN   250   // neg_im2cluster values are in [0, min(NUM_CLUSTER)) = [0,250)

// workspace float offsets
#define OFF_CENT_T   0          // 3*128*250 = 96000 floats (layout [h][d][c])

// K_prep: normalize centroid rows 0..249 of each hierarchy into transposed
// [h][d][c] layout; also zero the scalar output (stream order guarantees this
// kernel fully completes before K_main's atomics).
__global__ void kA_prep(const float* __restrict__ c0,
                        const float* __restrict__ c1,
                        const float* __restrict__ c2,
                        float* __restrict__ centT,
                        float* __restrict__ out) {
    if (blockIdx.x == 0 && threadIdx.x == 0) out[0] = 0.0f;
    int wid  = blockIdx.x * 4 + (threadIdx.x >> 6);
    int lane = threadIdx.x & 63;
    if (wid >= HH * NCN) return;
    int h = (wid >= 2 * NCN) ? 2 : (wid >= NCN ? 1 : 0);
    int c = wid - h * NCN;
    const float* cp = (h == 0) ? c0 : (h == 1) ? c1 : c2;
    const float2 v = *(const float2*)(cp + (size_t)c * DD + lane * 2);
    float ss = v.x * v.x + v.y * v.y;
    #pragma unroll
    for (int off = 32; off; off >>= 1) ss += __shfl_xor(ss, off);
    float inv = 1.0f / fmaxf(sqrtf(ss), 1e-12f);
    float* base = centT + h * (DD * NCN);
    base[(lane * 2)     * NCN + c] = v.x * inv;
    base[(lane * 2 + 1) * NCN + c] = v.y * inv;
}

// K_main: one block per sample b. Fuses:
//  1. se row normalization (3 waves, one per hierarchy) -> LDS
//  2. positive path (gather centroid, inline norm+dot)  -> LDS
//  3. sim table sim[h][c] for the 250 negative-eligible clusters -> LDS
//  4. negative-path loss over 1000 negatives via LDS lookups
//  5. block reduce + single atomicAdd of this sample's contribution
__global__ __launch_bounds__(256) void kB_main(
        const float* __restrict__ se,
        const float* __restrict__ c0,
        const float* __restrict__ c1,
        const float* __restrict__ c2,
        const int* __restrict__ i2c0,
        const int* __restrict__ i2c1,
        const int* __restrict__ i2c2,
        const int* __restrict__ index,
        const int* __restrict__ negc,
        const float* __restrict__ centT,
        float* __restrict__ out) {
    int b = blockIdx.x;
    int tid = threadIdx.x, wave = tid >> 6, lane = tid & 63;

    __shared__ float sse[HH * DD];
    __shared__ float ssim[HH * NCN];
    __shared__ int   slab[HH];
    __shared__ float ph[HH];
    __shared__ float wL[4], wT[4];

    // --- 1+2: se normalize + positive path (waves 0..2) ---
    if (wave < HH) {
        int h = wave;
        const float2 s = *(const float2*)(se + (size_t)b * (HH * DD) + h * DD + lane * 2);
        float ss = s.x * s.x + s.y * s.y;
        #pragma unroll
        for (int off = 32; off; off >>= 1) ss += __shfl_xor(ss, off);
        float inv = 1.0f / fmaxf(sqrtf(ss), 1e-12f);
        float2 sn = make_float2(s.x * inv, s.y * inv);
        sse[h * DD + lane * 2]     = sn.x;
        sse[h * DD + lane * 2 + 1] = sn.y;

        int idx = index[b];
        const int*   ip = (h == 0) ? i2c0 : (h == 1) ? i2c1 : i2c2;
        const float* cp = (h == 0) ? c0   : (h == 1) ? c1   : c2;
        int cidx = ip[idx];
        const float2 cv = *(const float2*)(cp + (size_t)cidx * DD + lane * 2);
        float dot = sn.x * cv.x + sn.y * cv.y;
        float csq = cv.x * cv.x + cv.y * cv.y;
        #pragma unroll
        for (int off = 32; off; off >>= 1) {
            dot += __shfl_xor(dot, off);
            csq += __shfl_xor(csq, off);
        }
        if (lane == 0) {
            float invc = 1.0f / fmaxf(sqrtf(csq), 1e-12f);
            ph[h]   = (dot * invc + 1.0f) * 0.5f;
            slab[h] = cidx;
        }
    }
    __syncthreads();

    // --- 3: sim table (750 dots of length 128 against L2-hot centT) ---
    for (int j = tid; j < HH * NCN; j += 256) {
        int h = (j >= 2 * NCN) ? 2 : (j >= NCN ? 1 : 0);
        int c = j - h * NCN;
        const float* ct = centT + h * (DD * NCN) + c;
        const float* sh = sse + h * DD;
        float acc = 0.0f;
        #pragma unroll 8
        for (int d = 0; d < DD; ++d) acc = fmaf(sh[d], ct[d * NCN], acc);
        ssim[j] = (acc + 1.0f) * 0.5f;
    }
    __syncthreads();

    // --- 4: negative-path loss ---
    int l0 = slab[0], l1 = slab[1], l2 = slab[2];
    float accL = 0.0f, accT = 0.0f;
    for (int n = tid; n < NNEG; n += 256) {
        const int* q = negc + ((size_t)b * NNEG + n) * HH;
        int i0 = q[0], i1 = q[1], i2 = q[2];
        float p = ssim[i0] * ssim[NCN + i1] * ssim[2 * NCN + i2];
        if (i0 != l0 || i1 != l1 || i2 != l2) {
            accL -= logf(1.0f - p + EPS);
            accT += 1.0f;
        }
    }
    #pragma unroll
    for (int off = 32; off; off >>= 1) {
        accL += __shfl_xor(accL, off);
        accT += __shfl_xor(accT, off);
    }
    if (lane == 0) { wL[wave] = accL; wT[wave] = accT; }
    __syncthreads();

    // --- 5: combine + atomic ---
    if (tid == 0) {
        float L = wL[0] + wL[1] + wL[2] + wL[3];
        float T = wT[0] + wT[1] + wT[2] + wT[3];
        float neg_b = L / (T + EPS);
        float pos_b = -logf(ph[0] * ph[1] * ph[2] + EPS);
        atomicAdd(out, (pos_b + neg_b) * (1.0f / (2.0f * BB)));
    }
}

extern "C" void kernel_launch(void* const* d_in, const int* in_sizes, int n_in,
                              void* d_out, int out_size, void* d_ws, size_t ws_size,
                              hipStream_t stream) {
    const float* se    = (const float*)d_in[0];
    const float* c0    = (const float*)d_in[1];
    const float* c1    = (const float*)d_in[2];
    const float* c2    = (const float*)d_in[3];
    const int*   i2c0  = (const int*)d_in[4];
    const int*   i2c1  = (const int*)d_in[5];
    const int*   i2c2  = (const int*)d_in[6];
    const int*   index = (const int*)d_in[7];
    const int*   negc  = (const int*)d_in[8];

    float* centT = (float*)d_ws + OFF_CENT_T;
    float* out   = (float*)d_out;

    // 750 centroid rows, 1 wave per row, 4 waves/block
    hipLaunchKernelGGL(kA_prep, dim3((HH * NCN + 3) / 4), dim3(256), 0, stream,
                       c0, c1, c2, centT, out);
    // one block per sample
    hipLaunchKernelGGL(kB_main, dim3(BB), dim3(256), 0, stream,
                       se, c0, c1, c2, i2c0, i2c1, i2c2, index, negc, centT, out);
}